// Round 6
// baseline (30410.727 us; speedup 1.0000x reference)
//
#include <hip/hip_runtime.h>
#include <cmath>

#define B_ 16
#define T_ 2048
#define D_ 512
#define H_ 512
#define NWG 256  // oversubscribed rnn_rec grid for XCD role claiming

// d_ws layout (zeroed at launch start):
//   u64 fast[B_][2][H_]  bytes [0,      131072)   L2 (sc0) exchange buffer
//   u64 slow[B_][2][H_]  bytes [131072, 262144)   L3 (agent) exchange buffer
//   u32 ctr[16]          bytes [262144, 262208)
//     ctr[0..7] per-XCD claim counts, ctr[8] registered WGs, ctr[9] overflow
#define WS_CTR_OFF ((size_t)2 * B_ * 2 * H_ * 8)

// ---------------------------------------------------------------------------
// Phase 1: XW[m, n] = x[m, :] @ W_xh[:, n] + bias[n] -> d_out.
// M = 32768, K = 512, N = 512. fp32, 128x128 tile, 8x8 acc per thread.
// ---------------------------------------------------------------------------
__global__ __launch_bounds__(256) void gemm_xw(
    const float* __restrict__ x,     // [M, K]
    const float* __restrict__ Wxh,   // [K, N]
    const float* __restrict__ bias,  // [N]
    float* __restrict__ out)         // [M, N]
{
    const int tid = threadIdx.x;
    const int n0 = blockIdx.x * 128;
    const int m0 = blockIdx.y * 128;

    __shared__ float As[8][132];  // [k][m], +4 pad
    __shared__ float Bs[8][132];  // [k][n]

    const int tx = tid & 15, ty = tid >> 4;
    float acc[8][8] = {};

    const int arow = tid >> 1;
    const int akq  = (tid & 1) * 4;
    const int brow = tid >> 5;
    const int bcol = (tid & 31) * 4;

    for (int k0 = 0; k0 < D_; k0 += 8) {
        float4 a4 = *(const float4*)(x + (size_t)(m0 + arow) * D_ + k0 + akq);
        float4 b4 = *(const float4*)(Wxh + (size_t)(k0 + brow) * H_ + n0 + bcol);
        __syncthreads();
        As[akq + 0][arow] = a4.x;
        As[akq + 1][arow] = a4.y;
        As[akq + 2][arow] = a4.z;
        As[akq + 3][arow] = a4.w;
        *(float4*)(&Bs[brow][bcol]) = b4;
        __syncthreads();
#pragma unroll
        for (int kk = 0; kk < 8; ++kk) {
            float4 a0 = *(const float4*)(&As[kk][ty * 8]);
            float4 a1 = *(const float4*)(&As[kk][ty * 8 + 4]);
            float4 b0 = *(const float4*)(&Bs[kk][tx * 8]);
            float4 b1 = *(const float4*)(&Bs[kk][tx * 8 + 4]);
            float a_[8] = {a0.x, a0.y, a0.z, a0.w, a1.x, a1.y, a1.z, a1.w};
            float b_[8] = {b0.x, b0.y, b0.z, b0.w, b1.x, b1.y, b1.z, b1.w};
#pragma unroll
            for (int i = 0; i < 8; ++i)
#pragma unroll
                for (int j = 0; j < 8; ++j) acc[i][j] += a_[i] * b_[j];
        }
    }

    const float4 bv0 = *(const float4*)(bias + n0 + tx * 8);
    const float4 bv1 = *(const float4*)(bias + n0 + tx * 8 + 4);
    const float bb[8] = {bv0.x, bv0.y, bv0.z, bv0.w, bv1.x, bv1.y, bv1.z, bv1.w};
#pragma unroll
    for (int i = 0; i < 8; ++i) {
        const int m = m0 + ty * 8 + i;
        float4 o0, o1;
        o0.x = acc[i][0] + bb[0]; o0.y = acc[i][1] + bb[1];
        o0.z = acc[i][2] + bb[2]; o0.w = acc[i][3] + bb[3];
        o1.x = acc[i][4] + bb[4]; o1.y = acc[i][5] + bb[5];
        o1.z = acc[i][6] + bb[6]; o1.w = acc[i][7] + bb[7];
        *(float4*)(out + (size_t)m * H_ + n0 + tx * 8)     = o0;
        *(float4*)(out + (size_t)m * H_ + n0 + tx * 8 + 4) = o1;
    }
}

// ---------------------------------------------------------------------------
// Phase 2: recurrence with XCD-aware role claiming.
// 256 WGs launched; each reads its physical XCD (s_getreg HW_REG_XCC_ID,
// HW-verified on gfx950) and claims a (batch, slice) role so that all 8
// slices of a batch share one XCD (XCD x owns batches 2x, 2x+1). One-time
// rendezvous (all 256 WGs co-resident: grid <= capacity) finalizes counts;
// deficit roles go to overflow WGs (their batches use the L3 slow path).
// Surplus WGs exit.
//
// Exchange = packed u64 (tag<<32 | float bits), double-buffered by tag&1.
//   FAST (batch fully XCD-local): producer store sc0 -> write-through L1
//   into the shared per-XCD L2; consumer load sc0 bypasses L1, reads L2.
//   ~200-300 cy RTT. (Round 3 failed only because blockIdx%8 != real XCD.)
//   SLOW: relaxed agent-scope atomics (L3 coherence point), as round 5.
// Producer dual-publishes (sc0 first, agent second); fast consumers have a
// sticky timeout fallback to slow -> no hangs, no staleness regardless of
// dispatch behavior (readiness tag is inside the naturally-atomic 8B word).
// Slot-reuse safety: vmcnt(0) guard at top of producer step (in-flight ops
// there are >=1 step old). Barriers are LDS-only (lgkmcnt).
// ---------------------------------------------------------------------------
#define FAST_SPIN (1 << 16)

__device__ __forceinline__ void bar_lds() {
    asm volatile("s_waitcnt lgkmcnt(0)\n\ts_barrier" ::: "memory");
}

__global__ __launch_bounds__(512, 2) void rnn_rec(
    const float* __restrict__ Whh,           // [H_][H_] row-major
    float* __restrict__ out,                 // [B_][T_][H_], pre-filled XW+b
    unsigned long long* __restrict__ ws)
{
    const int tid = threadIdx.x;
    __shared__ int sh_batch, sh_slice, sh_fast;
    unsigned int* ctr = (unsigned int*)((char*)ws + WS_CTR_OFF);

    // ---- one-time role claim (thread 0) ----
    if (tid == 0) {
        unsigned xcd;
        asm volatile("s_getreg_b32 %0, hwreg(HW_REG_XCC_ID)" : "=s"(xcd));
        xcd &= 7u;
        unsigned my = __hip_atomic_fetch_add(&ctr[xcd], 1u, __ATOMIC_ACQ_REL,
                                             __HIP_MEMORY_SCOPE_AGENT);
        __hip_atomic_fetch_add(&ctr[8], 1u, __ATOMIC_ACQ_REL,
                               __HIP_MEMORY_SCOPE_AGENT);
        while (__hip_atomic_load(&ctr[8], __ATOMIC_ACQUIRE,
                                 __HIP_MEMORY_SCOPE_AGENT) < (unsigned)NWG) {}
        int batch = -1, slice = 0;
        if (my < 16u) {
            batch = (int)(2u * xcd + (my >> 3));
            slice = (int)(my & 7u);
        } else {
            unsigned k = __hip_atomic_fetch_add(&ctr[9], 1u, __ATOMIC_ACQ_REL,
                                                __HIP_MEMORY_SCOPE_AGENT);
            for (int x = 0; x < 8; ++x) {
                unsigned c = __hip_atomic_load(&ctr[x], __ATOMIC_ACQUIRE,
                                               __HIP_MEMORY_SCOPE_AGENT);
                unsigned cl = c < 16u ? c : 16u;
                unsigned deficit = 16u - cl;
                if (k < deficit) {  // claim idx-th unclaimed role of XCD x
                    unsigned idx = cl + k;
                    batch = 2 * x + (int)(idx >> 3);
                    slice = (int)(idx & 7u);
                    break;
                }
                k -= deficit;
            }
        }
        int fast = 0;
        if (batch >= 0) {
            // batch 2h local iff cnt[h]>=8; batch 2h+1 local iff cnt[h]>=16
            unsigned hc = __hip_atomic_load(&ctr[batch >> 1], __ATOMIC_ACQUIRE,
                                            __HIP_MEMORY_SCOPE_AGENT);
            fast = (batch & 1) ? (hc >= 16u) : (hc >= 8u);
        }
        sh_batch = batch; sh_slice = slice; sh_fast = fast;
    }
    __syncthreads();
    const int b = sh_batch;
    if (b < 0) return;  // surplus WG
    const int s = sh_slice;
    bool use_fast = (sh_fast != 0);  // sticky, per thread

    const int j = tid & 63;   // column within slice
    const int p = tid >> 6;   // wave index == row block (rows 64p..64p+63)
    const int col = (s << 6) + j;

    __shared__ float h_lds[H_];
    __shared__ float part[8 * 64];

    // W slice: W_reg[r] = Whh[64p + r][col] (asm-defined -> not remat'able)
    float W_reg[64];
    {
        const float* wbase = Whh + (size_t)(p * 64) * H_ + col;
#pragma unroll
        for (int r = 0; r < 64; ++r) {
            const float* addr = wbase + (size_t)r * H_;
            asm volatile("global_load_dword %0, %1, off"
                         : "=v"(W_reg[r]) : "v"(addr));
        }
        asm volatile("s_waitcnt vmcnt(0)" ::: "memory");
    }

    h_lds[tid] = 0.0f;  // h_0 = 0
    __syncthreads();

    float* outb = out + (size_t)b * T_ * H_;
    unsigned long long* fastb = ws + (size_t)b * 2 * H_;
    unsigned long long* slowb = ws + (size_t)B_ * 2 * H_ + (size_t)b * 2 * H_;

    // xw prefetch pipeline, depth 3 (wave 0 consumes xw)
    float xw0 = 0.0f, xw1 = 0.0f, xw2 = 0.0f;
    if (p == 0) {
        xw0 = outb[(size_t)0 * H_ + col];
        xw1 = outb[(size_t)1 * H_ + col];
        xw2 = outb[(size_t)2 * H_ + col];
    }

    for (int t = 0; t < T_; ++t) {
        // ---- partial dot: rows [64p, 64p+64) of column `col` ----
        float acc = 0.0f;
        const float4* hv = (const float4*)(h_lds + (p << 6));
#pragma unroll
        for (int i = 0; i < 16; ++i) {
            float4 h4 = hv[i];
            acc += h4.x * W_reg[4 * i + 0];
            acc += h4.y * W_reg[4 * i + 1];
            acc += h4.z * W_reg[4 * i + 2];
            acc += h4.w * W_reg[4 * i + 3];
        }
        part[tid] = acc;
        bar_lds();  // (1) part ready; h_lds(t-1) fully consumed (LDS only)

        const unsigned int tag = (unsigned int)(t + 1);
        const size_t base = (size_t)((t + 1) & 1) * H_;

        if (p == 0) {
            // slot-reuse guard: everything in flight is >= 1 step old
            asm volatile("s_waitcnt vmcnt(0)" ::: "memory");
            float ssum = xw0;
#pragma unroll
            for (int q = 0; q < 8; ++q) ssum += part[q * 64 + j];
            union { unsigned int u; float f; } cv;
            cv.f = tanhf(ssum);
            unsigned long long pv =
                ((unsigned long long)tag << 32) | (unsigned long long)cv.u;
            // fast publish first (L2, what same-XCD pollers watch) ...
            unsigned long long* fdst = fastb + base + col;
            asm volatile("global_store_dwordx2 %0, %1, off sc0"
                         :: "v"(fdst), "v"(pv) : "memory");
            // ... then slow publish (L3, fallback + cross-XCD batches)
            __hip_atomic_store(slowb + base + col, pv, __ATOMIC_RELAXED,
                               __HIP_MEMORY_SCOPE_AGENT);
            outb[(size_t)t * H_ + col] = cv.f;  // final output (plain)
            h_lds[col] = cv.f;
            xw0 = xw1;
            xw1 = xw2;
            xw2 = (t + 3 < T_) ? outb[(size_t)(t + 3) * H_ + col] : 0.0f;
        } else {
            // gather one remote slice: wave p -> slice p; wave s (local
            // slice) covers slice 0 for producer-wave 0
            const int q = (p == s) ? 0 : p;
            const size_t idx = base + (q << 6) + j;
            unsigned long long v = 0;
            if (use_fast) {
                unsigned long long* fsrc = fastb + idx;
                int spins = FAST_SPIN;
                for (;;) {
                    asm volatile(
                        "global_load_dwordx2 %0, %1, off sc0\n\t"
                        "s_waitcnt vmcnt(0)"
                        : "=v"(v) : "v"(fsrc) : "memory");
                    if ((unsigned int)(v >> 32) >= tag) break;
                    if (--spins == 0) { use_fast = false; break; }
                }
            }
            if (!use_fast) {
                unsigned long long* ssrc = slowb + idx;
                do {
                    v = __hip_atomic_load(ssrc, __ATOMIC_RELAXED,
                                          __HIP_MEMORY_SCOPE_AGENT);
                } while ((unsigned int)(v >> 32) < tag);
            }
            union { unsigned int u; float f; } cv;
            cv.u = (unsigned int)v;
            h_lds[(q << 6) + j] = cv.f;
        }
        bar_lds();  // (2) h_lds now holds h_t (LDS only)
    }
}

extern "C" void kernel_launch(void* const* d_in, const int* in_sizes, int n_in,
                              void* d_out, int out_size, void* d_ws,
                              size_t ws_size, hipStream_t stream) {
    const float* x    = (const float*)d_in[0];  // [B,T,D]
    const float* Wxh  = (const float*)d_in[1];  // [D,H]
    const float* Whh  = (const float*)d_in[2];  // [H,H]
    const float* bias = (const float*)d_in[3];  // [H]
    // d_in[4] = A, unused in forward
    float* out = (float*)d_out;

    // zero fast+slow exchange buffers (tags start at 0) and claim counters
    hipMemsetAsync(d_ws, 0, WS_CTR_OFF + 16 * sizeof(unsigned int), stream);

    dim3 ggrid(H_ / 128, (B_ * T_) / 128, 1);
    gemm_xw<<<ggrid, 256, 0, stream>>>(x, Wxh, bias, out);

    rnn_rec<<<NWG, 512, 0, stream>>>(Whh, out, (unsigned long long*)d_ws);
}

// Round 7
// 4835.209 us; speedup vs baseline: 6.2894x; 6.2894x over previous
//
#include <hip/hip_runtime.h>
#include <cmath>

#define B_ 16
#define T_ 2048
#define D_ 512
#define H_ 512

// ---------------------------------------------------------------------------
// Phase 1: XW[m, n] = x[m, :] @ W_xh[:, n] + bias[n] -> d_out.
// M = 32768, K = 512, N = 512. fp32, 128x128 tile, 8x8 acc per thread.
// ---------------------------------------------------------------------------
__global__ __launch_bounds__(256) void gemm_xw(
    const float* __restrict__ x,     // [M, K]
    const float* __restrict__ Wxh,   // [K, N]
    const float* __restrict__ bias,  // [N]
    float* __restrict__ out)         // [M, N]
{
    const int tid = threadIdx.x;
    const int n0 = blockIdx.x * 128;
    const int m0 = blockIdx.y * 128;

    __shared__ float As[8][132];  // [k][m], +4 pad
    __shared__ float Bs[8][132];  // [k][n]

    const int tx = tid & 15, ty = tid >> 4;
    float acc[8][8] = {};

    const int arow = tid >> 1;
    const int akq  = (tid & 1) * 4;
    const int brow = tid >> 5;
    const int bcol = (tid & 31) * 4;

    for (int k0 = 0; k0 < D_; k0 += 8) {
        float4 a4 = *(const float4*)(x + (size_t)(m0 + arow) * D_ + k0 + akq);
        float4 b4 = *(const float4*)(Wxh + (size_t)(k0 + brow) * H_ + n0 + bcol);
        __syncthreads();
        As[akq + 0][arow] = a4.x;
        As[akq + 1][arow] = a4.y;
        As[akq + 2][arow] = a4.z;
        As[akq + 3][arow] = a4.w;
        *(float4*)(&Bs[brow][bcol]) = b4;
        __syncthreads();
#pragma unroll
        for (int kk = 0; kk < 8; ++kk) {
            float4 a0 = *(const float4*)(&As[kk][ty * 8]);
            float4 a1 = *(const float4*)(&As[kk][ty * 8 + 4]);
            float4 b0 = *(const float4*)(&Bs[kk][tx * 8]);
            float4 b1 = *(const float4*)(&Bs[kk][tx * 8 + 4]);
            float a_[8] = {a0.x, a0.y, a0.z, a0.w, a1.x, a1.y, a1.z, a1.w};
            float b_[8] = {b0.x, b0.y, b0.z, b0.w, b1.x, b1.y, b1.z, b1.w};
#pragma unroll
            for (int i = 0; i < 8; ++i)
#pragma unroll
                for (int j = 0; j < 8; ++j) acc[i][j] += a_[i] * b_[j];
        }
    }

    const float4 bv0 = *(const float4*)(bias + n0 + tx * 8);
    const float4 bv1 = *(const float4*)(bias + n0 + tx * 8 + 4);
    const float bb[8] = {bv0.x, bv0.y, bv0.z, bv0.w, bv1.x, bv1.y, bv1.z, bv1.w};
#pragma unroll
    for (int i = 0; i < 8; ++i) {
        const int m = m0 + ty * 8 + i;
        float4 o0, o1;
        o0.x = acc[i][0] + bb[0]; o0.y = acc[i][1] + bb[1];
        o0.z = acc[i][2] + bb[2]; o0.w = acc[i][3] + bb[3];
        o1.x = acc[i][4] + bb[4]; o1.y = acc[i][5] + bb[5];
        o1.z = acc[i][6] + bb[6]; o1.w = acc[i][7] + bb[7];
        *(float4*)(out + (size_t)m * H_ + n0 + tx * 8)     = o0;
        *(float4*)(out + (size_t)m * H_ + n0 + tx * 8 + 4) = o1;
    }
}

// ---------------------------------------------------------------------------
// Phase 2: recurrence, restructured for ONE barrier/step and no wave-0
// serialization. 8 WGs x 512 thr per batch (128 WGs); WG (b,s) owns h cols
// [64s,64s+64). Exchange: packed u64 (tag<<32 | float bits), RELAXED
// agent-scope (L3 coherence point - the only polling mechanism that works;
// sc0/L2 polling is L1-eviction-limited, confirmed rounds 3 & 6), slots
// double-buffered by tag&1 (reuse proven safe by the tag chain).
//
// Step structure (wave p, lane l):
//   1. poll slice p of h_t into registers (wave p's dot needs EXACTLY
//      slice p) -> wave-private h_lds write, lgkm wait, no barrier.
//      Wave s self-polls its own WG's slice via L3 (symmetric).
//   2. dot: partial for own col l over rows [64p,64p+64).
//   3. part[t&1][p][l] -> ONE barrier.
//   4. distributed reduce: 8 lanes per column (g=l&7), shfl_xor butterfly,
//      + xw (wave-private LDS prefetch, 2 ahead), tanh.
//      g==0 publishes (tag t+1), g==1 stores out[t], g==2 prefetches xw.
// part[] reuse at t+2 is ordered by: our tag-(t+1) publish follows each
// wave's part-read at t; any tag t+2 requires all tag t+1 -> safe.
// ---------------------------------------------------------------------------
__device__ __forceinline__ void bar_lds() {
    asm volatile("s_waitcnt lgkmcnt(0)\n\ts_barrier" ::: "memory");
}

__global__ __launch_bounds__(512, 2) void rnn_rec(
    const float* __restrict__ Whh,           // [H_][H_] row-major
    float* __restrict__ out,                 // [B_][T_][H_], pre-filled XW+b
    unsigned long long* __restrict__ ex)     // [B_][2][H_] packed (tag,val)
{
    const int tid = threadIdx.x;
    const int b = blockIdx.x & 15;
    const int s = blockIdx.x >> 4;
    const int l = tid & 63;   // lane within wave
    const int p = tid >> 6;   // wave index == h-slice this wave polls/uses

    __shared__ float h_lds[H_];        // wave-private 64-float slices
    __shared__ float part[2][8 * 68];  // [t&1][wave][col], stride 68
    __shared__ float xw_lds[2][64];    // [t&1][col], wave-private col ranges

    // W slice: W_reg[r] = Whh[64p + r][64s + l] (asm-defined -> must stay
    // in registers, cannot be rematerialized from memory)
    float W_reg[64];
    {
        const float* wbase = Whh + (size_t)(p * 64) * H_ + (s * 64 + l);
#pragma unroll
        for (int r = 0; r < 64; ++r) {
            const float* addr = wbase + (size_t)r * H_;
            asm volatile("global_load_dword %0, %1, off"
                         : "=v"(W_reg[r]) : "v"(addr));
        }
        asm volatile("s_waitcnt vmcnt(0)" ::: "memory");
    }

    float* outb = out + (size_t)b * T_ * H_;
    unsigned long long* exb = ex + (size_t)b * 2 * H_;

    h_lds[tid] = 0.0f;  // h_0 = 0
    if (tid < 128) {    // xw for t=0,1
        const int tt = tid >> 6;
        const int c  = tid & 63;
        xw_lds[tt][c] = outb[(size_t)tt * H_ + s * 64 + c];
    }
    __syncthreads();

    const int g    = l & 7;             // reduce-group lane
    const int cl   = p * 8 + (l >> 3);  // column (local) this thread reduces
    const int gcol = s * 64 + cl;       // same, global

    for (int t = 0; t < T_; ++t) {
        // ---- 1. poll slice p of h_t (skip at t=0: h_0 = 0, pre-zeroed) ----
        if (t > 0) {
            unsigned long long* src =
                exb + (size_t)(t & 1) * H_ + (p << 6) + l;
            unsigned long long v;
            do {
                v = __hip_atomic_load(src, __ATOMIC_RELAXED,
                                      __HIP_MEMORY_SCOPE_AGENT);
            } while ((unsigned int)(v >> 32) < (unsigned int)t);
            union { unsigned int u; float f; } cv;
            cv.u = (unsigned int)v;
            h_lds[(p << 6) + l] = cv.f;  // wave-private slice
            asm volatile("s_waitcnt lgkmcnt(0)" ::: "memory");
        }

        // ---- 2. dot: partial for own col l over rows [64p, 64p+64) ----
        float acc = 0.0f;
        const float4* hv = (const float4*)(h_lds + (p << 6));
#pragma unroll
        for (int i = 0; i < 16; ++i) {
            float4 h4 = hv[i];
            acc += h4.x * W_reg[4 * i + 0];
            acc += h4.y * W_reg[4 * i + 1];
            acc += h4.z * W_reg[4 * i + 2];
            acc += h4.w * W_reg[4 * i + 3];
        }
        part[t & 1][p * 68 + l] = acc;
        bar_lds();  // the ONE barrier: part[] ready across waves

        // ---- 3. distributed reduce + tanh + publish ----
        float v = part[t & 1][g * 68 + cl];
        v += __shfl_xor(v, 1);
        v += __shfl_xor(v, 2);
        v += __shfl_xor(v, 4);   // all 8 group lanes now hold the sum
        v += xw_lds[t & 1][cl];
        const float h = tanhf(v);

        const unsigned int tag = (unsigned int)(t + 1);
        if (g == 0) {
            union { unsigned int u; float f; } cv;
            cv.f = h;
            unsigned long long pv =
                ((unsigned long long)tag << 32) | (unsigned long long)cv.u;
            __hip_atomic_store(exb + (size_t)(tag & 1) * H_ + gcol, pv,
                               __ATOMIC_RELAXED, __HIP_MEMORY_SCOPE_AGENT);
        } else if (g == 1) {
            outb[(size_t)t * H_ + gcol] = h;  // final output
        } else if (g == 2 && t + 2 < T_) {
            // xw prefetch 2 ahead into the slot being freed this step
            // (wave-private columns -> no barrier needed)
            xw_lds[t & 1][cl] = outb[(size_t)(t + 2) * H_ + gcol];
        }
    }
}

extern "C" void kernel_launch(void* const* d_in, const int* in_sizes, int n_in,
                              void* d_out, int out_size, void* d_ws,
                              size_t ws_size, hipStream_t stream) {
    const float* x    = (const float*)d_in[0];  // [B,T,D]
    const float* Wxh  = (const float*)d_in[1];  // [D,H]
    const float* Whh  = (const float*)d_in[2];  // [H,H]
    const float* bias = (const float*)d_in[3];  // [H]
    // d_in[4] = A, unused in forward
    float* out = (float*)d_out;

    // exchange buffer: [16][2][512] x 8B = 128 KB; tags must start at 0
    // (harness poisons ws with 0xAA before every launch)
    hipMemsetAsync(d_ws, 0, (size_t)B_ * 2 * H_ * sizeof(unsigned long long),
                   stream);

    dim3 ggrid(H_ / 128, (B_ * T_) / 128, 1);
    gemm_xw<<<ggrid, 256, 0, stream>>>(x, Wxh, bias, out);

    rnn_rec<<<128, 512, 0, stream>>>(Whh, out, (unsigned long long*)d_ws);
}